// Round 8
// baseline (116.987 us; speedup 1.0000x reference)
//
#include <hip/hip_runtime.h>
#include <hip/hip_bf16.h>

#define IN 8192
#define OUT 8192

typedef __bf16 bf16x8 __attribute__((ext_vector_type(8)));
typedef float f32x4 __attribute__((ext_vector_type(4)));
typedef unsigned short u16;
typedef unsigned int u32;
typedef u32 u32x4 __attribute__((ext_vector_type(4)));

#define MFMA(a, b, c) __builtin_amdgcn_mfma_f32_16x16x32_bf16(a, b, c, 0, 0, 0)

static __device__ __forceinline__ u16 f2bf(float v) {
    __hip_bfloat16 h = __float2bfloat16(v);
    return __builtin_bit_cast(u16, h);
}
static __device__ __forceinline__ float bf2f(u16 h) {
    union { u32 u; float f; } cv; cv.u = ((u32)h) << 16; return cv.f;
}
static __device__ __forceinline__ void split_hl(float v, u16& hi, u16& lo) {
    hi = f2bf(v);
    lo = f2bf(v - bf2f(hi));
}
static __device__ __forceinline__ bf16x8 ld8(const u16* p) {
    return *reinterpret_cast<const bf16x8*>(p);
}

// ================= pre: block (b,lc) computes Z[:, 16lc:+16], all-coalesced global reads =================
// xp = x[b]/shw (coalesced -> LDS); X[j][n] = xp[vinp[j*128+n]] (LDS gather);
// W = X @ v2c^T (MFMA); Z = v1 @ W^T (MFMA); scan voutp -> scatter xt; Spart[b][lc].
__global__ __launch_bounds__(256)
void pre_kernel(const float* __restrict__ x, const float* __restrict__ shw,
                const int* __restrict__ vinp, const int* __restrict__ voutp,
                const float* __restrict__ v1, const float* __restrict__ v2,
                u16* __restrict__ xt, float* __restrict__ Spart, int* __restrict__ cnt) {
    __shared__ __align__(16) char smem[69632];
    __shared__ float sred[4];
    float* xp  = (float*)smem;                     // [8192] f32           [0,32768)
    u16* V1hi  = (u16*)smem;                       // overlay after X:     [0,9216)
    u16* V1lo  = (u16*)(smem + 9216);              //                      [9216,18432)
    u16* V2hi  = (u16*)(smem + 18432);             // [16][136]            [18432,22784)
    u16* V2lo  = (u16*)(smem + 22784);             //                      [22784,27136)
    u16* WThi  = (u16*)(smem + 27136);             // [16][72]             [27136,29440)
    u16* WTlo  = (u16*)(smem + 29440);             //                      [29440,31744)
    u16* Xhi   = (u16*)(smem + 32768);             // [64][136]            [32768,50176)
    u16* Xlo   = (u16*)(smem + 50176);             //                      [50176,67584)
    u16* Zl    = (u16*)(smem + 67584);             // [64][16]             [67584,69632)
    const int tid = threadIdx.x;
    const int b = blockIdx.x >> 3, lc = blockIdx.x & 7;
    const int lane = tid & 63, w = tid >> 6;
    const int l15 = lane & 15, l4 = lane >> 4;
    if (blockIdx.x == 0 && tid == 0) *cnt = 0;     // reset K2 counter

    #pragma unroll
    for (int it = 0; it < 32; ++it) {              // coalesced x/shw -> LDS
        int q = tid + it * 256;
        xp[q] = x[b * IN + q] / shw[q];
    }
    __syncthreads();
    #pragma unroll
    for (int it = 0; it < 32; ++it) {              // X[j][n] via LDS gather
        int e = tid + it * 256;
        float v = xp[vinp[e]];
        u16 h, l; split_hl(v, h, l);
        int idx = (e >> 7) * 136 + (e & 127);
        Xhi[idx] = h; Xlo[idx] = l;
    }
    __syncthreads();                               // xp dead; overlay v1/v2c/WT
    #pragma unroll
    for (int it = 0; it < 16; ++it) {              // v1 [i][j] natural
        int e = tid + it * 256;
        u16 h, l; split_hl(v1[e], h, l);
        int idx = (e >> 6) * 72 + (e & 63);
        V1hi[idx] = h; V1lo[idx] = l;
    }
    #pragma unroll
    for (int it = 0; it < 8; ++it) {               // v2 chunk rows [r][n]
        int e = tid + it * 256;
        int r = e >> 7, n = e & 127;
        u16 h, l; split_hl(v2[(lc * 16 + r) * 128 + n], h, l);
        V2hi[r * 136 + n] = h; V2lo[r * 136 + n] = l;
    }
    __syncthreads();

    // stage A: W[j][r] = sum_n X[j,n]*v2c[r,n]  (M=64 j, N=16 r, K=128). m-tile = w.
    f32x4 acc = {0.f, 0.f, 0.f, 0.f};
    #pragma unroll
    for (int ks = 0; ks < 4; ++ks) {
        int ao = (w * 16 + l15) * 136 + ks * 32 + l4 * 8;
        int bo = l15 * 136 + ks * 32 + l4 * 8;
        bf16x8 ah = ld8(&Xhi[ao]), al = ld8(&Xlo[ao]);
        bf16x8 bh = ld8(&V2hi[bo]), bl = ld8(&V2lo[bo]);
        acc = MFMA(ah, bh, acc); acc = MFMA(ah, bl, acc); acc = MFMA(al, bh, acc);
    }
    #pragma unroll
    for (int r = 0; r < 4; ++r) {                  // W^T[r=l15][j]
        int j = w * 16 + l4 * 4 + r;
        u16 h, l; split_hl(acc[r], h, l);
        WThi[l15 * 72 + j] = h; WTlo[l15 * 72 + j] = l;
    }
    __syncthreads();

    // stage B: Z[i][r] = sum_j v1[i,j]*W^T[r,j]  (M=64 i, N=16 r, K=64). m-tile = w.
    f32x4 z = {0.f, 0.f, 0.f, 0.f};
    #pragma unroll
    for (int ks = 0; ks < 2; ++ks) {
        int ao = (w * 16 + l15) * 72 + ks * 32 + l4 * 8;
        int bo = l15 * 72 + ks * 32 + l4 * 8;
        bf16x8 ah = ld8(&V1hi[ao]), al = ld8(&V1lo[ao]);
        bf16x8 bh = ld8(&WThi[bo]), bl = ld8(&WTlo[bo]);
        z = MFMA(ah, bh, z); z = MFMA(ah, bl, z); z = MFMA(al, bh, z);
    }
    float ssum = 0.f;
    #pragma unroll
    for (int r = 0; r < 4; ++r) {
        int i = w * 16 + l4 * 4 + r;
        u16 zb = f2bf(z[r]);
        Zl[i * 16 + l15] = zb;
        ssum += bf2f(zb);
    }
    #pragma unroll
    for (int off = 32; off; off >>= 1) ssum += __shfl_down(ssum, off, 64);
    if (lane == 0) sred[w] = ssum;
    __syncthreads();
    if (tid == 0) Spart[b * 8 + lc] = (sred[0] + sred[1]) + (sred[2] + sred[3]);

    // scan voutp (coalesced); hits -> scattered 2B xt stores
    #pragma unroll
    for (int it = 0; it < 32; ++it) {
        int p = tid + it * 256;
        int v = voutp[p];
        if (((v >> 4) & 7) == lc)
            xt[(size_t)b * IN + p] = Zl[(v >> 7) * 16 + (v & 15)];
    }
}

// ================= K2: gemm (512 blocks x 256 thr, R3 form) + last-128-finisher post =================
__global__ __launch_bounds__(256)
void gemm_post_kernel(const int* __restrict__ qw, const u16* __restrict__ xt,
                      const float* __restrict__ Spart, const float* __restrict__ scale,
                      const float* __restrict__ u1, const float* __restrict__ u2,
                      const float* __restrict__ bias,
                      const int* __restrict__ uinp, const int* __restrict__ uoutp,
                      float* __restrict__ G, float* __restrict__ out,
                      int* __restrict__ cnt) {
    __shared__ __align__(16) char smem[78336];
    __shared__ int sOld;
    const int tid = threadIdx.x, bid = blockIdx.x;
    const int lane = tid & 63, w = tid >> 6;
    const int l15 = lane & 15, l4 = lane >> 4;

    // ---------------- gemm phase (R3 validated form) ----------------
    {
        u16* sA = (u16*)smem;                      // [16][2056] = 65792 B
        const int bx = bid & 127, by = bid >> 7;
        const int o0 = bx * 64, k0 = by * 2048;
        #pragma unroll
        for (int i = 0; i < 16; ++i) {
            int idx = tid + i * 256;
            int r = idx >> 8, c = idx & 255;
            *reinterpret_cast<u32x4*>(&sA[r * 2056 + c * 8]) =
                *reinterpret_cast<const u32x4*>(&xt[(size_t)r * IN + k0 + c * 8]);
        }
        __syncthreads();
        const int o = o0 + w * 16 + l15;
        const int* qp = qw + (size_t)(k0 / 8 + l4) * OUT + o;
        f32x4 acc = {0.f, 0.f, 0.f, 0.f};
        #pragma unroll 8
        for (int kt = 0; kt < 64; ++kt) {
            u32 q = (u32)qp[(size_t)kt * 4 * OUT];
            bf16x8 a = ld8(&sA[l15 * 2056 + kt * 32 + l4 * 8]);
            u32 ev = q & 0x0F0F0F0Fu, od = (q >> 4) & 0x0F0F0F0Fu;
            float f0, f1, f2, f3, f4, f5, f6, f7;
            asm("v_cvt_f32_ubyte0 %0, %1" : "=v"(f0) : "v"(ev));
            asm("v_cvt_f32_ubyte0 %0, %1" : "=v"(f1) : "v"(od));
            asm("v_cvt_f32_ubyte1 %0, %1" : "=v"(f2) : "v"(ev));
            asm("v_cvt_f32_ubyte1 %0, %1" : "=v"(f3) : "v"(od));
            asm("v_cvt_f32_ubyte2 %0, %1" : "=v"(f4) : "v"(ev));
            asm("v_cvt_f32_ubyte2 %0, %1" : "=v"(f5) : "v"(od));
            asm("v_cvt_f32_ubyte3 %0, %1" : "=v"(f6) : "v"(ev));
            asm("v_cvt_f32_ubyte3 %0, %1" : "=v"(f7) : "v"(od));
            u32 p0, p1, p2, p3;
            asm("v_cvt_pk_bf16_f32 %0, %1, %2" : "=v"(p0) : "v"(f0), "v"(f1));
            asm("v_cvt_pk_bf16_f32 %0, %1, %2" : "=v"(p1) : "v"(f2), "v"(f3));
            asm("v_cvt_pk_bf16_f32 %0, %1, %2" : "=v"(p2) : "v"(f4), "v"(f5));
            asm("v_cvt_pk_bf16_f32 %0, %1, %2" : "=v"(p3) : "v"(f6), "v"(f7));
            u32x4 pk = {p0, p1, p2, p3};
            acc = MFMA(a, __builtin_bit_cast(bf16x8, pk), acc);
        }
        float* g = G + ((size_t)by * 16 + l4 * 4) * OUT + o;
        #pragma unroll
        for (int r = 0; r < 4; ++r) g[(size_t)r * OUT] = acc[r];
    }

    // ---------------- counter; last 128 finishers run post chunks ----------------
    __threadfence();
    if (tid == 0) sOld = atomicAdd(cnt, 1);
    __syncthreads();
    const int old = sOld;
    if (old < 384) return;
    if (tid == 0) {
        while (atomicAdd(cnt, 0) < 512) __builtin_amdgcn_s_sleep(4);
    }
    __syncthreads();
    __threadfence();
    const int cid = old - 384;
    const int b = cid >> 3, lc = cid & 7;

    // ---------------- post chunk (b,lc): all-coalesced global reads ----------------
    u16* inv  = (u16*)smem;                        // [8192]   [0,16384)
    u16* OGhi = (u16*)(smem + 16384);              // [64][136] [16384,33792)
    u16* OGlo = (u16*)(smem + 33792);              //           [33792,51200)
    u16* U1hi = (u16*)(smem + 51200);              // [64][72]  [51200,60416)
    u16* U1lo = (u16*)(smem + 60416);              //           [60416,69632)
    u16* U2hi = (u16*)(smem + 69632);              // [16][136] [69632,73984)
    u16* U2lo = (u16*)(smem + 73984);              //           [73984,78336)
    u16* YThi = (u16*)smem;                        // overlay inv after og: [0,2304)
    u16* YTlo = (u16*)(smem + 2304);               //           [2304,4608)
    float* Zp = (float*)(smem + 4608);             // [64][16]  [4608,8704)

    float Sb = 0.f;
    #pragma unroll
    for (int c = 0; c < 8; ++c) Sb += Spart[b * 8 + c];

    #pragma unroll
    for (int it = 0; it < 32; ++it) {              // inverse of uoutp
        int e = tid + it * 256;
        inv[uoutp[e]] = (u16)e;
    }
    __syncthreads();
    #pragma unroll
    for (int it = 0; it < 32; ++it) {              // og: coalesced G/scale, LDS scatter
        int o = tid + it * 256;
        float gs = G[(size_t)b * OUT + o] + G[(size_t)(16 + b) * OUT + o]
                 + G[(size_t)(32 + b) * OUT + o] + G[(size_t)(48 + b) * OUT + o];
        float v = scale[o] * (gs * (2.0f / 15.0f) - Sb);
        int e = inv[o];
        u16 h, l; split_hl(v, h, l);
        int idx = (e >> 7) * 136 + (e & 127);
        OGhi[idx] = h; OGlo[idx] = l;
    }
    #pragma unroll
    for (int it = 0; it < 16; ++it) {              // u1^T [i][j]
        int e = tid + it * 256;
        u16 h, l; split_hl(u1[e], h, l);
        int idx = (e & 63) * 72 + (e >> 6);
        U1hi[idx] = h; U1lo[idx] = l;
    }
    #pragma unroll
    for (int it = 0; it < 8; ++it) {               // u2 col-chunk^T [lr][n]
        int e = tid + it * 256;
        int lr = e & 15, n = e >> 4;
        u16 h, l; split_hl(u2[n * 128 + lc * 16 + lr], h, l);
        U2hi[lr * 136 + n] = h; U2lo[lr * 136 + n] = l;
    }
    __syncthreads();

    // stage A': Y[j][lr] = sum_n og[j,n]*u2c[lr,n]  (M=64,N=16,K=128). m-tile = w.
    f32x4 acc = {0.f, 0.f, 0.f, 0.f};
    #pragma unroll
    for (int ks = 0; ks < 4; ++ks) {
        int ao = (w * 16 + l15) * 136 + ks * 32 + l4 * 8;
        int bo = l15 * 136 + ks * 32 + l4 * 8;
        bf16x8 ah = ld8(&OGhi[ao]), al = ld8(&OGlo[ao]);
        bf16x8 bh = ld8(&U2hi[bo]), bl = ld8(&U2lo[bo]);
        acc = MFMA(ah, bh, acc); acc = MFMA(ah, bl, acc); acc = MFMA(al, bh, acc);
    }
    #pragma unroll
    for (int r = 0; r < 4; ++r) {                  // Y^T[lr=l15][j]
        int j = w * 16 + l4 * 4 + r;
        u16 h, l; split_hl(acc[r], h, l);
        YThi[l15 * 72 + j] = h; YTlo[l15 * 72 + j] = l;
    }
    __syncthreads();

    // stage B': Zp[i][lr] = sum_j u1T[i,j]*Y^T[lr,j]  (M=64,N=16,K=64). m-tile = w.
    f32x4 z = {0.f, 0.f, 0.f, 0.f};
    #pragma unroll
    for (int ks = 0; ks < 2; ++ks) {
        int ao = (w * 16 + l15) * 72 + ks * 32 + l4 * 8;
        int bo = l15 * 72 + ks * 32 + l4 * 8;
        bf16x8 ah = ld8(&U1hi[ao]), al = ld8(&U1lo[ao]);
        bf16x8 bh = ld8(&YThi[bo]), bl = ld8(&YTlo[bo]);
        z = MFMA(ah, bh, z); z = MFMA(ah, bl, z); z = MFMA(al, bh, z);
    }
    #pragma unroll
    for (int r = 0; r < 4; ++r)
        Zp[(w * 16 + l4 * 4 + r) * 16 + l15] = z[r];
    __syncthreads();

    #pragma unroll
    for (int it = 0; it < 32; ++it) {              // scan uinp + coalesced bias
        int p = tid + it * 256;
        int u = uinp[p];
        float bv = bias[p];
        if (((u >> 4) & 7) == lc)
            out[(size_t)b * OUT + p] = Zp[(u >> 7) * 16 + (u & 15)] + bv;
    }
}

extern "C" void kernel_launch(void* const* d_in, const int* in_sizes, int n_in,
                              void* d_out, int out_size, void* d_ws, size_t ws_size,
                              hipStream_t stream) {
    const float* x     = (const float*)d_in[0];
    const int*   qw    = (const int*)d_in[1];
    const float* scale = (const float*)d_in[2];
    const float* shw   = (const float*)d_in[3];
    const float* v1    = (const float*)d_in[4];
    const float* v2    = (const float*)d_in[5];
    const float* u1    = (const float*)d_in[6];
    const float* u2    = (const float*)d_in[7];
    const float* bias  = (const float*)d_in[8];
    const int* vinp  = (const int*)d_in[9];
    const int* voutp = (const int*)d_in[10];
    const int* uinp  = (const int*)d_in[11];
    const int* uoutp = (const int*)d_in[12];
    float* out = (float*)d_out;

    char* ws = (char*)d_ws;
    u16*   xt    = (u16*)ws;                       // 256 KiB  [16][8192] bf16
    float* G     = (float*)(ws + (256 << 10));     // 2 MiB    [4][16][8192] f32
    float* Spart = (float*)(ws + (2304 << 10));    // 512 B    [16][8] f32
    int*   cnt   = (int*)(ws + (2305 << 10));      // 4 B

    pre_kernel<<<128, 256, 0, stream>>>(x, shw, vinp, voutp, v1, v2, xt, Spart, cnt);
    gemm_post_kernel<<<512, 256, 0, stream>>>(qw, xt, Spart, scale, u1, u2, bias,
                                              uinp, uoutp, G, out, cnt);
}

// Round 9
// 63.251 us; speedup vs baseline: 1.8496x; 1.8496x over previous
//
#include <hip/hip_runtime.h>
#include <hip/hip_bf16.h>

#define IN 8192
#define OUT 8192

typedef __bf16 bf16x8 __attribute__((ext_vector_type(8)));
typedef float f32x4 __attribute__((ext_vector_type(4)));
typedef unsigned short u16;
typedef unsigned int u32;
typedef u32 u32x4 __attribute__((ext_vector_type(4)));

#define MFMA(a, b, c) __builtin_amdgcn_mfma_f32_16x16x32_bf16(a, b, c, 0, 0, 0)

static __device__ __forceinline__ u16 f2bf(float v) {
    __hip_bfloat16 h = __float2bfloat16(v);
    return __builtin_bit_cast(u16, h);
}
static __device__ __forceinline__ float bf2f(u16 h) {
    union { u32 u; float f; } cv; cv.u = ((u32)h) << 16; return cv.f;
}
static __device__ __forceinline__ void split_hl(float v, u16& hi, u16& lo) {
    hi = f2bf(v);
    lo = f2bf(v - bf2f(hi));
}
static __device__ __forceinline__ bf16x8 ld8(const u16* p) {
    return *reinterpret_cast<const bf16x8*>(p);
}

// ================= pre: butterfly-in + scatter to bf16 xt + S[b]  (R3 form, validated @53.4) =================
__global__ __launch_bounds__(1024)
void pre_kernel(const float* __restrict__ x, const float* __restrict__ shw,
                const int* __restrict__ vinp, const int* __restrict__ voutp,
                const float* __restrict__ v1, const float* __restrict__ v2,
                u16* __restrict__ xt, float* __restrict__ S) {
    __shared__ alignas(16) u16 sV1[2][64 * 72];     // v1 hi/lo, [i][j] stride 72
    __shared__ alignas(16) u16 sXb[2][128 * 72];    // X^T [n][j] stride 72; reused as T [i][k] stride 136
    __shared__ alignas(16) u16 sV2[2][128 * 136];   // v2 [l][k] stride 136
    __shared__ float sred[16];
    const int tid = threadIdx.x, b = blockIdx.x;
    const int lane = tid & 63, w = tid >> 6;
    const int l15 = lane & 15, l4 = lane >> 4;

    #pragma unroll
    for (int it = 0; it < 4; ++it) {                // v1: 4096
        int e = tid + it * 1024;
        u16 h, l; split_hl(v1[e], h, l);
        int idx = (e >> 6) * 72 + (e & 63);
        sV1[0][idx] = h; sV1[1][idx] = l;
    }
    #pragma unroll
    for (int it = 0; it < 16; ++it) {               // v2: 16384, natural [l][k]
        int e = tid + it * 1024;
        u16 h, l; split_hl(v2[e], h, l);
        int idx = (e >> 7) * 136 + (e & 127);
        sV2[0][idx] = h; sV2[1][idx] = l;
    }
    int qidx[8];
    #pragma unroll
    for (int it = 0; it < 8; ++it) qidx[it] = vinp[tid + it * 1024];
    #pragma unroll
    for (int it = 0; it < 8; ++it) {                // X gather, store transposed [n][j]
        int q = qidx[it];
        float v = x[b * IN + q] / shw[q];
        u16 h, l; split_hl(v, h, l);
        int e = tid + it * 1024;
        int idx = (e & 127) * 72 + (e >> 7);
        sXb[0][idx] = h; sXb[1][idx] = l;
    }
    __syncthreads();

    // stage1: T = v1 @ X  (M=64,N=128,K=64). wave: n-tile nt, m-half mh.
    const int nt = w & 7, mh = w >> 3;
    f32x4 acc0 = {0.f, 0.f, 0.f, 0.f}, acc1 = {0.f, 0.f, 0.f, 0.f};
    #pragma unroll
    for (int ks = 0; ks < 2; ++ks) {
        int boff = (nt * 16 + l15) * 72 + ks * 32 + l4 * 8;
        bf16x8 bh = ld8(&sXb[0][boff]), bl = ld8(&sXb[1][boff]);
        int a0 = (mh * 32 + l15) * 72 + ks * 32 + l4 * 8;
        int a1 = a0 + 16 * 72;
        bf16x8 ah0 = ld8(&sV1[0][a0]), al0 = ld8(&sV1[1][a0]);
        bf16x8 ah1 = ld8(&sV1[0][a1]), al1 = ld8(&sV1[1][a1]);
        acc0 = MFMA(ah0, bh, acc0); acc0 = MFMA(ah0, bl, acc0); acc0 = MFMA(al0, bh, acc0);
        acc1 = MFMA(ah1, bh, acc1); acc1 = MFMA(ah1, bl, acc1); acc1 = MFMA(al1, bh, acc1);
    }
    __syncthreads();                                // all waves done reading sXb
    u16* Thi = sXb[0]; u16* Tlo = sXb[1];           // T [i][k] stride 136
    #pragma unroll
    for (int m = 0; m < 2; ++m) {
        f32x4 a = m ? acc1 : acc0;
        #pragma unroll
        for (int r = 0; r < 4; ++r) {
            int i = mh * 32 + m * 16 + l4 * 4 + r;
            u16 h, l; split_hl(a[r], h, l);
            Thi[i * 136 + nt * 16 + l15] = h;
            Tlo[i * 136 + nt * 16 + l15] = l;
        }
    }
    __syncthreads();

    // stage2: Z = T @ v2^T  (M=64,N=128,K=128)
    f32x4 z0 = {0.f, 0.f, 0.f, 0.f}, z1 = {0.f, 0.f, 0.f, 0.f};
    #pragma unroll
    for (int ks = 0; ks < 4; ++ks) {
        int boff = (nt * 16 + l15) * 136 + ks * 32 + l4 * 8;
        bf16x8 bh = ld8(&sV2[0][boff]), bl = ld8(&sV2[1][boff]);
        int a0 = (mh * 32 + l15) * 136 + ks * 32 + l4 * 8;
        int a1 = a0 + 16 * 136;
        bf16x8 ah0 = ld8(&Thi[a0]), al0 = ld8(&Tlo[a0]);
        bf16x8 ah1 = ld8(&Thi[a1]), al1 = ld8(&Tlo[a1]);
        z0 = MFMA(ah0, bh, z0); z0 = MFMA(ah0, bl, z0); z0 = MFMA(al0, bh, z0);
        z1 = MFMA(ah1, bh, z1); z1 = MFMA(ah1, bl, z1); z1 = MFMA(al1, bh, z1);
    }
    __syncthreads();
    u16* Zl = &sV1[0][0];                           // 8192 u16, reuse v1 region
    #pragma unroll
    for (int m = 0; m < 2; ++m) {
        f32x4 zz = m ? z1 : z0;
        #pragma unroll
        for (int r = 0; r < 4; ++r) {
            int i = mh * 32 + m * 16 + l4 * 4 + r;
            Zl[i * 128 + nt * 16 + l15] = f2bf(zz[r]);
        }
    }
    __syncthreads();
    float ssum = 0.f;
    #pragma unroll
    for (int it = 0; it < 8; ++it) {
        int p = tid + it * 1024;
        u16 zb = Zl[voutp[p]];
        xt[(size_t)b * IN + p] = zb;
        ssum += bf2f(zb);
    }
    #pragma unroll
    for (int off = 32; off; off >>= 1) ssum += __shfl_down(ssum, off, 64);
    if (lane == 0) sred[w] = ssum;
    __syncthreads();
    if (tid == 0) {
        float t = 0.f;
        #pragma unroll
        for (int i = 0; i < 16; ++i) t += sred[i];
        S[b] = t;
    }
}

// ================= qgemm v3: no LDS, no barriers; register-pipelined qw stream =================
// block (bx, by): o-range [bx*64,+64), k-plane [by*2048,+2048). 4 waves = 4 o-groups.
// A-frags read straight from L2-resident xt; qw loaded in 16-deep register batches with
// one-batch-ahead prefetch (32 KB/CU in flight -> HBM-saturated).
__global__ __launch_bounds__(256, 2)
void qgemm_kernel(const int* __restrict__ qw, const u16* __restrict__ xt,
                  float* __restrict__ G) {
    const int tid = threadIdx.x;
    const int lane = tid & 63, w = tid >> 6;
    const int l15 = lane & 15, l4 = lane >> 4;
    const int o = blockIdx.x * 64 + w * 16 + l15;
    const int k0 = blockIdx.y * 2048;
    const int* qp = qw + (size_t)(k0 / 8 + l4) * OUT + o;
    const u16* ap = xt + (size_t)l15 * IN + k0 + l4 * 8;
    f32x4 acc = {0.f, 0.f, 0.f, 0.f};

    u32 qa[16], qb[16];
    #pragma unroll
    for (int j = 0; j < 16; ++j) qa[j] = (u32)qp[(size_t)j * 4 * OUT];

    #pragma unroll 1
    for (int b4 = 0; b4 < 4; ++b4) {
        const int* qpn = qp + (size_t)(b4 + 1) * 16 * 4 * OUT;
        if (b4 < 3) {
            #pragma unroll
            for (int j = 0; j < 16; ++j) qb[j] = (u32)qpn[(size_t)j * 4 * OUT];
        }
        const u16* apb = ap + b4 * 16 * 32;
        #pragma unroll
        for (int j = 0; j < 16; ++j) {
            u32 q = qa[j];
            bf16x8 a = ld8(apb + j * 32);
            u32 ev = q & 0x0F0F0F0Fu, od = (q >> 4) & 0x0F0F0F0Fu;
            float f0, f1, f2, f3, f4, f5, f6, f7;
            asm("v_cvt_f32_ubyte0 %0, %1" : "=v"(f0) : "v"(ev));
            asm("v_cvt_f32_ubyte0 %0, %1" : "=v"(f1) : "v"(od));
            asm("v_cvt_f32_ubyte1 %0, %1" : "=v"(f2) : "v"(ev));
            asm("v_cvt_f32_ubyte1 %0, %1" : "=v"(f3) : "v"(od));
            asm("v_cvt_f32_ubyte2 %0, %1" : "=v"(f4) : "v"(ev));
            asm("v_cvt_f32_ubyte2 %0, %1" : "=v"(f5) : "v"(od));
            asm("v_cvt_f32_ubyte3 %0, %1" : "=v"(f6) : "v"(ev));
            asm("v_cvt_f32_ubyte3 %0, %1" : "=v"(f7) : "v"(od));
            u32 p0, p1, p2, p3;
            asm("v_cvt_pk_bf16_f32 %0, %1, %2" : "=v"(p0) : "v"(f0), "v"(f1));
            asm("v_cvt_pk_bf16_f32 %0, %1, %2" : "=v"(p1) : "v"(f2), "v"(f3));
            asm("v_cvt_pk_bf16_f32 %0, %1, %2" : "=v"(p2) : "v"(f4), "v"(f5));
            asm("v_cvt_pk_bf16_f32 %0, %1, %2" : "=v"(p3) : "v"(f6), "v"(f7));
            u32x4 pk = {p0, p1, p2, p3};
            acc = MFMA(a, __builtin_bit_cast(bf16x8, pk), acc);
        }
        #pragma unroll
        for (int j = 0; j < 16; ++j) qa[j] = qb[j];
    }

    float* g = G + ((size_t)blockIdx.y * 16 + l4 * 4) * OUT + o;
    #pragma unroll
    for (int r = 0; r < 4; ++r) g[(size_t)r * OUT] = acc[r];
}

// ================= post: plane-reduce + scale/offset + butterfly-out + bias  (R3 form, validated @53.4) =================
__global__ __launch_bounds__(1024)
void post_kernel(const float* __restrict__ G, const float* __restrict__ S,
                 const int* __restrict__ uoutp, const int* __restrict__ uinp,
                 const float* __restrict__ scale, const float* __restrict__ u1,
                 const float* __restrict__ u2, const float* __restrict__ bias,
                 float* __restrict__ out) {
    __shared__ alignas(16) u16 sU1[2][64 * 72];     // u1^T [i][j] stride 72
    __shared__ alignas(16) u16 sOG[2][128 * 72];    // og^T [n][j] stride 72; reused as t2 [i][k] stride 136
    __shared__ alignas(16) u16 sU2[2][128 * 136];   // u2^T [l][k] stride 136; reused as Zp f32[8192]
    const int tid = threadIdx.x, b = blockIdx.x;
    const int lane = tid & 63, w = tid >> 6;
    const int l15 = lane & 15, l4 = lane >> 4;
    const float Sb = S[b];

    #pragma unroll
    for (int it = 0; it < 4; ++it) {                // u1^T: u1[j*64+i] -> [i][j]
        int e = tid + it * 1024;
        u16 h, l; split_hl(u1[e], h, l);
        int idx = (e & 63) * 72 + (e >> 6);
        sU1[0][idx] = h; sU1[1][idx] = l;
    }
    #pragma unroll
    for (int it = 0; it < 16; ++it) {               // u2^T: u2[k*128+l] -> [l][k]
        int e = tid + it * 1024;
        u16 h, l; split_hl(u2[e], h, l);
        int idx = (e & 127) * 136 + (e >> 7);
        sU2[0][idx] = h; sU2[1][idx] = l;
    }
    int oo[8];
    #pragma unroll
    for (int it = 0; it < 8; ++it) oo[it] = uoutp[tid + it * 1024];
    #pragma unroll
    for (int it = 0; it < 8; ++it) {
        int o = oo[it];
        float gs = G[(size_t)b * OUT + o] + G[(size_t)(16 + b) * OUT + o]
                 + G[(size_t)(32 + b) * OUT + o] + G[(size_t)(48 + b) * OUT + o];
        float v = scale[o] * (gs * (2.0f / 15.0f) - Sb);
        u16 h, l; split_hl(v, h, l);
        int e = tid + it * 1024;
        int idx = (e & 127) * 72 + (e >> 7);        // og^T [n][j]
        sOG[0][idx] = h; sOG[1][idx] = l;
    }
    __syncthreads();

    // stage1: t2 = u1^T @ og  (M=64,N=128,K=64)
    const int nt = w & 7, mh = w >> 3;
    f32x4 acc0 = {0.f, 0.f, 0.f, 0.f}, acc1 = {0.f, 0.f, 0.f, 0.f};
    #pragma unroll
    for (int ks = 0; ks < 2; ++ks) {
        int boff = (nt * 16 + l15) * 72 + ks * 32 + l4 * 8;
        bf16x8 bh = ld8(&sOG[0][boff]), bl = ld8(&sOG[1][boff]);
        int a0 = (mh * 32 + l15) * 72 + ks * 32 + l4 * 8;
        int a1 = a0 + 16 * 72;
        bf16x8 ah0 = ld8(&sU1[0][a0]), al0 = ld8(&sU1[1][a0]);
        bf16x8 ah1 = ld8(&sU1[0][a1]), al1 = ld8(&sU1[1][a1]);
        acc0 = MFMA(ah0, bh, acc0); acc0 = MFMA(ah0, bl, acc0); acc0 = MFMA(al0, bh, acc0);
        acc1 = MFMA(ah1, bh, acc1); acc1 = MFMA(ah1, bl, acc1); acc1 = MFMA(al1, bh, acc1);
    }
    __syncthreads();
    u16* Thi = sOG[0]; u16* Tlo = sOG[1];           // t2 [i][k] stride 136
    #pragma unroll
    for (int m = 0; m < 2; ++m) {
        f32x4 a = m ? acc1 : acc0;
        #pragma unroll
        for (int r = 0; r < 4; ++r) {
            int i = mh * 32 + m * 16 + l4 * 4 + r;
            u16 h, l; split_hl(a[r], h, l);
            Thi[i * 136 + nt * 16 + l15] = h;
            Tlo[i * 136 + nt * 16 + l15] = l;
        }
    }
    __syncthreads();

    // stage2: Zp = t2 @ u2  (M=64,N=128,K=128)
    f32x4 z0 = {0.f, 0.f, 0.f, 0.f}, z1 = {0.f, 0.f, 0.f, 0.f};
    #pragma unroll
    for (int ks = 0; ks < 4; ++ks) {
        int boff = (nt * 16 + l15) * 136 + ks * 32 + l4 * 8;
        bf16x8 bh = ld8(&sU2[0][boff]), bl = ld8(&sU2[1][boff]);
        int a0 = (mh * 32 + l15) * 136 + ks * 32 + l4 * 8;
        int a1 = a0 + 16 * 136;
        bf16x8 ah0 = ld8(&Thi[a0]), al0 = ld8(&Tlo[a0]);
        bf16x8 ah1 = ld8(&Thi[a1]), al1 = ld8(&Tlo[a1]);
        z0 = MFMA(ah0, bh, z0); z0 = MFMA(ah0, bl, z0); z0 = MFMA(al0, bh, z0);
        z1 = MFMA(ah1, bh, z1); z1 = MFMA(ah1, bl, z1); z1 = MFMA(al1, bh, z1);
    }
    __syncthreads();                                // all waves done reading sU2
    float* Zp = reinterpret_cast<float*>(&sU2[0][0]);
    #pragma unroll
    for (int m = 0; m < 2; ++m) {
        f32x4 zz = m ? z1 : z0;
        #pragma unroll
        for (int r = 0; r < 4; ++r) {
            int i = mh * 32 + m * 16 + l4 * 4 + r;
            Zp[i * 128 + nt * 16 + l15] = zz[r];
        }
    }
    __syncthreads();
    #pragma unroll
    for (int it = 0; it < 8; ++it) {
        int p = tid + it * 1024;
        out[(size_t)b * OUT + p] = Zp[uinp[p]] + bias[p];
    }
}

extern "C" void kernel_launch(void* const* d_in, const int* in_sizes, int n_in,
                              void* d_out, int out_size, void* d_ws, size_t ws_size,
                              hipStream_t stream) {
    const float* x     = (const float*)d_in[0];
    const int*   qw    = (const int*)d_in[1];
    const float* scale = (const float*)d_in[2];
    const float* shw   = (const float*)d_in[3];
    const float* v1    = (const float*)d_in[4];
    const float* v2    = (const float*)d_in[5];
    const float* u1    = (const float*)d_in[6];
    const float* u2    = (const float*)d_in[7];
    const float* bias  = (const float*)d_in[8];
    const int* vinp  = (const int*)d_in[9];
    const int* voutp = (const int*)d_in[10];
    const int* uinp  = (const int*)d_in[11];
    const int* uoutp = (const int*)d_in[12];
    float* out = (float*)d_out;

    char* ws = (char*)d_ws;
    u16*   xt = (u16*)ws;                           // 256 KiB  [16][8192] bf16
    float* G  = (float*)(ws + (256 << 10));         // 2 MiB    [4][16][8192] f32
    float* S  = (float*)(ws + (2304 << 10));        // 64 B     [16] f32

    pre_kernel<<<16, 1024, 0, stream>>>(x, shw, vinp, voutp, v1, v2, xt, S);
    qgemm_kernel<<<dim3(128, 4), 256, 0, stream>>>(qw, xt, G);
    post_kernel<<<16, 1024, 0, stream>>>(G, S, uoutp, uinp, scale, u1, u2, bias, out);
}